// Round 9
// baseline (478.074 us; speedup 1.0000x reference)
//
#include <hip/hip_runtime.h>
#include <math.h>

#define N_NODES 50000
#define N_EDGES 800000
#define IN_DIM 128
#define ED_DIM 32
#define NH 4
#define CH 16
#define HC 64
#define NG 64
#define NCL 2
#define NEG_SLOPE 0.2f
#define LN_EPS 1e-5f
#define NBLK1 196  // ceil(50000/256)

// ---------- fold We @ ae -> Ve[32][8]  (k = layer*4 + head) ----------
__global__ void k_ve(const float* __restrict__ We1, const float* __restrict__ ae1,
                     const float* __restrict__ We2, const float* __restrict__ ae2,
                     float* __restrict__ Ve) {
    int t = threadIdx.x;            // 256 threads
    int d = t >> 3, k = t & 7;
    int l = k >> 2, h = k & 3;
    const float* We = l ? We2 : We1;
    const float* ae = l ? ae2 : ae1;
    float s = 0.f;
    #pragma unroll
    for (int c = 0; c < CH; ++c) s += We[d * HC + h * CH + c] * ae[h * CH + c];
    Ve[d * 8 + k] = s;
}

// ---------- degree histogram; atomic return = rank of edge within its row ----------
__global__ void k_hist(const int* __restrict__ dst, int* __restrict__ cnt,
                       int* __restrict__ rank_e) {
    int e = blockIdx.x * 256 + threadIdx.x;
    if (e < N_EDGES) rank_e[e] = atomicAdd(&cnt[dst[e]], 1);
}

// ---------- 3-phase exclusive scan of cnt -> row_start ----------
__global__ void k_scan_local(const int* __restrict__ cnt, int* __restrict__ tmp_ex,
                             int* __restrict__ bsum) {
    __shared__ int sd[256];
    int t = threadIdx.x, idx = blockIdx.x * 256 + t;
    int v = (idx < N_NODES) ? cnt[idx] : 0;
    sd[t] = v; __syncthreads();
    for (int off = 1; off < 256; off <<= 1) {
        int add = (t >= off) ? sd[t - off] : 0;
        __syncthreads();
        sd[t] += add;
        __syncthreads();
    }
    if (idx < N_NODES) tmp_ex[idx] = sd[t] - v;
    if (t == 255) bsum[blockIdx.x] = sd[t];
}

__global__ void k_scan_bsums(const int* __restrict__ bsum, int* __restrict__ boff) {
    __shared__ int sd[256];
    int t = threadIdx.x;
    int v = (t < NBLK1) ? bsum[t] : 0;
    sd[t] = v; __syncthreads();
    for (int off = 1; off < 256; off <<= 1) {
        int add = (t >= off) ? sd[t - off] : 0;
        __syncthreads();
        sd[t] += add;
        __syncthreads();
    }
    boff[t] = sd[t] - v;
}

__global__ void k_scan_final(const int* __restrict__ tmp_ex, const int* __restrict__ boff,
                             int* __restrict__ row_start) {
    int idx = blockIdx.x * 256 + threadIdx.x;
    if (idx < N_NODES) row_start[idx] = tmp_ex[idx] + boff[blockIdx.x];
    if (idx == 0) row_start[N_NODES] = N_EDGES;
}

// ---------- scatter edge id to precomputed slot (no atomics) ----------
__global__ void k_perm(const int* __restrict__ dst, const int* __restrict__ rank_e,
                       const int* __restrict__ row_start, int* __restrict__ perm_csr) {
    int e = blockIdx.x * 256 + threadIdx.x;
    if (e >= N_EDGES) return;
    int pos = row_start[dst[e]] + rank_e[e];
    perm_csr[pos] = e;
}

// ---------- pure streaming: ea -> ale8 (edge order) ----------
__global__ void k_edge(const float* __restrict__ ea, const float* __restrict__ Ve,
                       float* __restrict__ ale8) {
    __shared__ float sVe[ED_DIM * 8];
    int t = threadIdx.x;
    if (t < ED_DIM * 8) sVe[t] = Ve[t];
    __syncthreads();
    int e = blockIdx.x * 256 + t;
    if (e >= N_EDGES) return;
    float a[8];
    #pragma unroll
    for (int k = 0; k < 8; ++k) a[k] = 0.f;
    const float4* er4 = (const float4*)(ea + (long long)e * ED_DIM);
    #pragma unroll
    for (int q = 0; q < ED_DIM / 4; ++q) {
        float4 v = er4[q];
        float ev[4] = {v.x, v.y, v.z, v.w};
        #pragma unroll
        for (int u = 0; u < 4; ++u) {
            #pragma unroll
            for (int k = 0; k < 8; ++k) a[k] += ev[u] * sVe[(q * 4 + u) * 8 + k];
        }
    }
    float4* ap = (float4*)(ale8 + (long long)e * 8);
    ap[0] = make_float4(a[0], a[1], a[2], a[3]);
    ap[1] = make_float4(a[4], a[5], a[6], a[7]);
}

// ---------- gather (L3-hot) into CSR-ordered streams ----------
__global__ void k_gather(const int* __restrict__ perm, const int* __restrict__ srcI,
                         const float* __restrict__ ale8, int* __restrict__ src_csr,
                         float4* __restrict__ ale1, float4* __restrict__ ale2) {
    int i = blockIdx.x * 256 + threadIdx.x;
    if (i >= N_EDGES) return;
    int e = perm[i];
    const float4* a = (const float4*)(ale8 + (long long)e * 8);
    float4 a0 = a[0];
    float4 a1 = a[1];
    src_csr[i] = srcI[e];
    ale1[i] = a0;
    ale2[i] = a1;
}

// ---------- xw = X @ W  (+ fused per-head al_src / al_dst), 16 nodes/block ----------
// Inner loop: X via wave-uniform float4 LDS broadcasts (free), W via
// conflict-free b32 — 8 LDS instr per 4 k-steps instead of 20.
template<int K>
__global__ void k_xw(const float* __restrict__ X, const float* __restrict__ W,
                     const float* __restrict__ AS, const float* __restrict__ AD,
                     float* __restrict__ XW, float* __restrict__ ALS, float* __restrict__ ALD) {
    __shared__ float sW[K * HC];
    __shared__ float sX[16 * K];
    int t = threadIdx.x;
    for (int i = t; i < K * HC; i += 256) sW[i] = W[i];
    int nb = blockIdx.x * 16;
    for (int i = t; i < 16 * K; i += 256) sX[i] = X[(long long)nb * K + i];
    __syncthreads();
    int sub = t >> 6, j = t & 63;
    float acc[4] = {0.f, 0.f, 0.f, 0.f};
    #pragma unroll 4
    for (int k = 0; k < K; k += 4) {
        float4 xv0 = *(const float4*)&sX[(sub) * K + k];
        float4 xv1 = *(const float4*)&sX[(sub + 4) * K + k];
        float4 xv2 = *(const float4*)&sX[(sub + 8) * K + k];
        float4 xv3 = *(const float4*)&sX[(sub + 12) * K + k];
        float w0 = sW[(k + 0) * HC + j];
        float w1 = sW[(k + 1) * HC + j];
        float w2 = sW[(k + 2) * HC + j];
        float w3 = sW[(k + 3) * HC + j];
        acc[0] += xv0.x * w0 + xv0.y * w1 + xv0.z * w2 + xv0.w * w3;
        acc[1] += xv1.x * w0 + xv1.y * w1 + xv1.z * w2 + xv1.w * w3;
        acc[2] += xv2.x * w0 + xv2.y * w1 + xv2.z * w2 + xv2.w * w3;
        acc[3] += xv3.x * w0 + xv3.y * w1 + xv3.z * w2 + xv3.w * w3;
    }
    float as_ = AS[j], ad_ = AD[j];
    #pragma unroll
    for (int q = 0; q < 4; ++q) {
        int n = nb + sub + 4 * q;
        XW[(long long)n * HC + j] = acc[q];
        float vs = acc[q] * as_, vd = acc[q] * ad_;
        #pragma unroll
        for (int m = 1; m < 16; m <<= 1) { vs += __shfl_xor(vs, m); vd += __shfl_xor(vd, m); }
        if ((j & 15) == 0) {
            int h = j >> 4;
            ALS[n * 4 + h] = vs; ALD[n * 4 + h] = vd;
        }
    }
}

// ---------- wave-per-node softmax aggregation (+self-loop, bias/ReLU[/LN]) ----------
// Plain exp (no max shift): alphas are bounded (|a| <~ 10) by construction.
// Unroll 8: 32 independent loads in flight per wave to hide L2 gather latency.
template<bool DO_LN>
__global__ void k_agg(const int* __restrict__ rs, const int* __restrict__ srcs,
                      const float* __restrict__ ale,
                      const float* __restrict__ ALS, const float* __restrict__ ALD,
                      const float* __restrict__ XW, const float* __restrict__ bias,
                      const float* __restrict__ gam, const float* __restrict__ bet,
                      float* __restrict__ OUT) {
    int n = (blockIdx.x * blockDim.x + threadIdx.x) >> 6;
    if (n >= N_NODES) return;
    int lane = threadIdx.x & 63;
    int h = lane >> 4;
    int e0 = rs[n], e1 = rs[n + 1];
    float adn = ALD[n * 4 + h];
    float acc0 = 0.f, l0 = 0.f, as0 = 0.f;
    float acc1 = 0.f, l1 = 0.f, as1 = 0.f;
    float acc2 = 0.f, l2 = 0.f, as2 = 0.f;
    float acc3 = 0.f, l3 = 0.f, as3 = 0.f;
    int e = e0;
    for (; e + 7 < e1; e += 8) {
        int s0_ = srcs[e], s1_ = srcs[e + 1], s2_ = srcs[e + 2], s3_ = srcs[e + 3];
        int s4_ = srcs[e + 4], s5_ = srcs[e + 5], s6_ = srcs[e + 6], s7_ = srcs[e + 7];
        float ae0 = ale[(e) * 4 + h],     ae1v = ale[(e + 1) * 4 + h];
        float ae2v = ale[(e + 2) * 4 + h], ae3 = ale[(e + 3) * 4 + h];
        float ae4 = ale[(e + 4) * 4 + h], ae5 = ale[(e + 5) * 4 + h];
        float ae6 = ale[(e + 6) * 4 + h], ae7 = ale[(e + 7) * 4 + h];
        float x0 = XW[s0_ * HC + lane], x1 = XW[s1_ * HC + lane];
        float x2 = XW[s2_ * HC + lane], x3 = XW[s3_ * HC + lane];
        float x4 = XW[s4_ * HC + lane], x5 = XW[s5_ * HC + lane];
        float x6 = XW[s6_ * HC + lane], x7 = XW[s7_ * HC + lane];
        float a0 = ALS[s0_ * 4 + h] + adn + ae0;
        float a1 = ALS[s1_ * 4 + h] + adn + ae1v;
        float a2 = ALS[s2_ * 4 + h] + adn + ae2v;
        float a3 = ALS[s3_ * 4 + h] + adn + ae3;
        float a4 = ALS[s4_ * 4 + h] + adn + ae4;
        float a5 = ALS[s5_ * 4 + h] + adn + ae5;
        float a6 = ALS[s6_ * 4 + h] + adn + ae6;
        float a7 = ALS[s7_ * 4 + h] + adn + ae7;
        a0 = a0 > 0.f ? a0 : NEG_SLOPE * a0;
        a1 = a1 > 0.f ? a1 : NEG_SLOPE * a1;
        a2 = a2 > 0.f ? a2 : NEG_SLOPE * a2;
        a3 = a3 > 0.f ? a3 : NEG_SLOPE * a3;
        a4 = a4 > 0.f ? a4 : NEG_SLOPE * a4;
        a5 = a5 > 0.f ? a5 : NEG_SLOPE * a5;
        a6 = a6 > 0.f ? a6 : NEG_SLOPE * a6;
        a7 = a7 > 0.f ? a7 : NEG_SLOPE * a7;
        float q0 = __expf(a0), q1 = __expf(a1), q2 = __expf(a2), q3 = __expf(a3);
        float q4 = __expf(a4), q5 = __expf(a5), q6 = __expf(a6), q7 = __expf(a7);
        acc0 += q0 * x0 + q4 * x4; l0 += q0 + q4; as0 += ae0 + ae4;
        acc1 += q1 * x1 + q5 * x5; l1 += q1 + q5; as1 += ae1v + ae5;
        acc2 += q2 * x2 + q6 * x6; l2 += q2 + q6; as2 += ae2v + ae6;
        acc3 += q3 * x3 + q7 * x7; l3 += q3 + q7; as3 += ae3 + ae7;
    }
    for (; e < e1; ++e) {
        int sA = srcs[e];
        float aeA = ale[(e) * 4 + h];
        float xA = XW[sA * HC + lane];
        float aA = ALS[sA * 4 + h] + adn + aeA;
        aA = aA > 0.f ? aA : NEG_SLOPE * aA;
        float qA = __expf(aA);
        acc0 += qA * xA; l0 += qA; as0 += aeA;
    }
    // self loop: ale_self = mean of row's ale (linearity of edge projection)
    int d = e1 - e0;
    float invd = 1.f / (float)(d > 0 ? d : 1);
    float aSelf = ALS[n * 4 + h] + adn + (as0 + as1 + as2 + as3) * invd;
    aSelf = aSelf > 0.f ? aSelf : NEG_SLOPE * aSelf;
    float pS = __expf(aSelf);
    float acc = (acc0 + acc1) + (acc2 + acc3) + pS * XW[n * HC + lane];
    float l = (l0 + l1) + (l2 + l3) + pS;
    float v = acc / (l + 1e-16f) + bias[lane];
    v = fmaxf(v, 0.f);
    if (DO_LN) {
        float s1 = v;
        #pragma unroll
        for (int mm = 1; mm < 64; mm <<= 1) s1 += __shfl_xor(s1, mm);
        float mean = s1 * (1.f / 64.f);
        float dd = v - mean;
        float s2 = dd * dd;
        #pragma unroll
        for (int mm = 1; mm < 64; mm <<= 1) s2 += __shfl_xor(s2, mm);
        float var = s2 * (1.f / 64.f);
        v = dd * rsqrtf(var + LN_EPS) * gam[lane] + bet[lane];
    }
    OUT[(long long)n * HC + lane] = v;
}

// ---------- global max pool by (sorted) batch; values >= 0 ----------
__global__ void k_pool(const float* __restrict__ H2, const int* __restrict__ batch,
                       float* __restrict__ pooled) {
    int j = threadIdx.x & 63;
    int r = threadIdx.x >> 6;          // 4 rows in parallel
    int base = blockIdx.x * 128;
    int gcur = -1; float rm = 0.f;
    for (int n = base + r; n < base + 128 && n < N_NODES; n += 4) {
        int g = batch[n];
        if (g != gcur) {
            if (gcur >= 0) atomicMax((unsigned int*)&pooled[gcur * HC + j], __float_as_uint(rm));
            gcur = g; rm = 0.f;
        }
        rm = fmaxf(rm, H2[(long long)n * HC + j]);
    }
    if (gcur >= 0) atomicMax((unsigned int*)&pooled[gcur * HC + j], __float_as_uint(rm));
}

// ---------- head: fc1 + LN + relu + fc2 + log_softmax ----------
__global__ void k_head(const float* __restrict__ pooled,
                       const float* __restrict__ fw1, const float* __restrict__ fb1,
                       const float* __restrict__ g2, const float* __restrict__ be2,
                       const float* __restrict__ fw2, const float* __restrict__ fb2,
                       float* __restrict__ out) {
    int g = blockIdx.x;
    int j = threadIdx.x;                // 64 threads, lanes 0..31 active for math
    float z = 0.f;
    if (j < 32) {
        for (int k = 0; k < HC; ++k) z += pooled[g * HC + k] * fw1[k * 32 + j];
        z += fb1[j];
    }
    float s1 = (j < 32) ? z : 0.f;
    for (int m = 1; m < 32; m <<= 1) s1 += __shfl_xor(s1, m, 32);
    float mean = s1 * (1.f / 32.f);
    float d = z - mean;
    float s2 = (j < 32) ? d * d : 0.f;
    for (int m = 1; m < 32; m <<= 1) s2 += __shfl_xor(s2, m, 32);
    float var = s2 * (1.f / 32.f);
    float zz = 0.f;
    if (j < 32) {
        zz = d * rsqrtf(var + LN_EPS) * g2[j] + be2[j];
        zz = fmaxf(zz, 0.f);
    }
    float p0 = (j < 32) ? zz * fw2[j * NCL + 0] : 0.f;
    float p1 = (j < 32) ? zz * fw2[j * NCL + 1] : 0.f;
    for (int m = 1; m < 32; m <<= 1) { p0 += __shfl_xor(p0, m, 32); p1 += __shfl_xor(p1, m, 32); }
    if (j == 0) {
        float l0 = p0 + fb2[0], l1 = p1 + fb2[1];
        float mx = fmaxf(l0, l1);
        float ls = mx + logf(__expf(l0 - mx) + __expf(l1 - mx));
        out[g * NCL + 0] = l0 - ls;
        out[g * NCL + 1] = l1 - ls;
    }
}

extern "C" void kernel_launch(void* const* d_in, const int* in_sizes, int n_in,
                              void* d_out, int out_size, void* d_ws, size_t ws_size,
                              hipStream_t stream) {
    const float* x   = (const float*)d_in[0];
    const float* ea  = (const float*)d_in[1];
    const float* W1  = (const float*)d_in[2];
    const float* as1 = (const float*)d_in[3];
    const float* ad1 = (const float*)d_in[4];
    const float* We1 = (const float*)d_in[5];
    const float* ae1 = (const float*)d_in[6];
    const float* b1  = (const float*)d_in[7];
    const float* W2  = (const float*)d_in[8];
    const float* as2 = (const float*)d_in[9];
    const float* ad2 = (const float*)d_in[10];
    const float* We2 = (const float*)d_in[11];
    const float* ae2 = (const float*)d_in[12];
    const float* b2  = (const float*)d_in[13];
    const float* g1  = (const float*)d_in[14];
    const float* be1 = (const float*)d_in[15];
    const float* fw1 = (const float*)d_in[16];
    const float* fb1 = (const float*)d_in[17];
    const float* g2  = (const float*)d_in[18];
    const float* be2 = (const float*)d_in[19];
    const float* fw2 = (const float*)d_in[20];
    const float* fb2 = (const float*)d_in[21];
    const int* eidx  = (const int*)d_in[22];
    const int* batch = (const int*)d_in[23];
    const int* srcI = eidx;
    const int* dstI = eidx + N_EDGES;

    char* w = (char*)d_ws;
    auto alloc = [&](size_t bytes) { char* p = w; w += (bytes + 255) & ~(size_t)255; return p; };
    int*   cnt       = (int*)  alloc((size_t)N_NODES * 4);
    int*   row_start = (int*)  alloc((size_t)(N_NODES + 1) * 4);
    int*   rank_e    = (int*)  alloc((size_t)N_EDGES * 4);
    int*   tmp_ex    = (int*)  alloc((size_t)N_NODES * 4);
    int*   bsum      = (int*)  alloc(256 * 4);
    int*   boff      = (int*)  alloc(256 * 4);
    float* Ve        = (float*)alloc(ED_DIM * 8 * 4);
    int*   perm_csr  = (int*)  alloc((size_t)N_EDGES * 4);
    int*   src_csr   = (int*)  alloc((size_t)N_EDGES * 4);
    float* ale8      = (float*)alloc((size_t)N_EDGES * 8 * 4);
    float4* ale1     = (float4*)alloc((size_t)N_EDGES * 16);
    float4* ale2     = (float4*)alloc((size_t)N_EDGES * 16);
    float* xw1       = (float*)alloc((size_t)N_NODES * HC * 4);   // reused as xw2
    float* als1      = (float*)alloc((size_t)N_NODES * 4 * 4);
    float* ald1      = (float*)alloc((size_t)N_NODES * 4 * 4);
    float* h1        = (float*)alloc((size_t)N_NODES * HC * 4);   // reused as h2
    float* als2      = (float*)alloc((size_t)N_NODES * 4 * 4);
    float* ald2      = (float*)alloc((size_t)N_NODES * 4 * 4);
    float* pooled    = (float*)alloc((size_t)NG * HC * 4);
    float* xw2 = xw1;   // lifetime of xw1 ends at k_agg<true>
    float* h2  = h1;    // lifetime of h1 ends at k_xw<HC>

    hipMemsetAsync(cnt, 0, (size_t)N_NODES * 4, stream);
    hipMemsetAsync(pooled, 0, (size_t)NG * HC * 4, stream);

    k_ve<<<1, 256, 0, stream>>>(We1, ae1, We2, ae2, Ve);
    k_hist<<<N_EDGES / 256, 256, 0, stream>>>(dstI, cnt, rank_e);
    k_scan_local<<<NBLK1, 256, 0, stream>>>(cnt, tmp_ex, bsum);
    k_scan_bsums<<<1, 256, 0, stream>>>(bsum, boff);
    k_scan_final<<<NBLK1, 256, 0, stream>>>(tmp_ex, boff, row_start);
    k_edge<<<N_EDGES / 256, 256, 0, stream>>>(ea, Ve, ale8);
    k_perm<<<N_EDGES / 256, 256, 0, stream>>>(dstI, rank_e, row_start, perm_csr);
    k_gather<<<N_EDGES / 256, 256, 0, stream>>>(perm_csr, srcI, ale8, src_csr, ale1, ale2);

    // Layer 1: xw + attention logits, aggregate with fused bias/ReLU/LayerNorm
    k_xw<IN_DIM><<<N_NODES / 16, 256, 0, stream>>>(x, W1, as1, ad1, xw1, als1, ald1);
    k_agg<true><<<N_NODES / 4, 256, 0, stream>>>(row_start, src_csr, (const float*)ale1,
                                                 als1, ald1, xw1, b1, g1, be1, h1);
    // Layer 2: fused bias/ReLU only
    k_xw<HC><<<N_NODES / 16, 256, 0, stream>>>(h1, W2, as2, ad2, xw2, als2, ald2);
    k_agg<false><<<N_NODES / 4, 256, 0, stream>>>(row_start, src_csr, (const float*)ale2,
                                                  als2, ald2, xw2, b2, nullptr, nullptr, h2);

    k_pool<<<(N_NODES + 127) / 128, 256, 0, stream>>>(h2, batch, pooled);
    k_head<<<NG, 64, 0, stream>>>(pooled, fw1, fb1, g2, be2, fw2, fb2, (float*)d_out);
}